// Round 2
// baseline (382.699 us; speedup 1.0000x reference)
//
#include <hip/hip_runtime.h>

#define HIDDEN 1024
#define NG 20
#define BATCH 512
#define SEQ 1024
#define VOCAB 128

// output offsets (flat concat of (wind, kappa, phi))
#define WIND_OFF  0
#define KAPPA_OFF (BATCH * VOCAB)                 // 65536
#define PHI_OFF   (BATCH * VOCAB + BATCH * NG)    // 75776

// ---------------- k1: linear + gates + phi (one block per batch row) --------
__global__ __launch_bounds__(256) void gates_phi(
    const float* __restrict__ win,    // [B, H]
    const float* __restrict__ kprev,  // [B, NG]
    const float* __restrict__ W,      // [3*NG, H]
    const float* __restrict__ bias,   // [3*NG]
    float*       __restrict__ out,    // wind | kappa | phi
    float*       __restrict__ phi_ws) // [B, SEQ] scratch
{
    const int b    = blockIdx.x;
    const int tid  = threadIdx.x;
    const int lane = tid & 63;
    const int wave = tid >> 6;   // 0..3

    __shared__ float lin_s[3 * NG];
    __shared__ float alpha_s[NG], beta_s[NG], kappa_s[NG];

    // zero the wind accumulator region (k2 atomicAdds into it)
    if (tid < VOCAB) out[WIND_OFF + (size_t)b * VOCAB + tid] = 0.f;

    // Phase A: lin[j] = win[b,:] . W[j,:] + bias[j]  (wave per j)
    const float* wrow = win + (size_t)b * HIDDEN;
    for (int j = wave; j < 3 * NG; j += 4) {
        const float* Wrow = W + (size_t)j * HIDDEN;
        float acc = 0.f;
        #pragma unroll
        for (int t = 0; t < HIDDEN / 64; ++t)
            acc = fmaf(wrow[t * 64 + lane], Wrow[t * 64 + lane], acc);
        #pragma unroll
        for (int off = 32; off > 0; off >>= 1)
            acc += __shfl_down(acc, off, 64);
        if (lane == 0) lin_s[j] = acc + bias[j];
    }
    __syncthreads();

    // Phase B: gates
    if (tid < 3 * NG) {
        float e = __expf(lin_s[tid]);
        if (tid < NG) {
            alpha_s[tid] = e;
        } else if (tid < 2 * NG) {
            beta_s[tid - NG] = e;
        } else {
            int k = tid - 2 * NG;
            float kp = kprev[(size_t)b * NG + k] + e * 0.05f;
            kappa_s[k] = kp;
            out[KAPPA_OFF + (size_t)b * NG + k] = kp;
        }
    }
    __syncthreads();

    // Phase C: phi[u]
    for (int u = tid; u < SEQ; u += 256) {
        float uu = (float)u;
        float p = 0.f;
        #pragma unroll
        for (int k = 0; k < NG; ++k) {
            float d = kappa_s[k] - uu;
            p = fmaf(alpha_s[k], __expf(-beta_s[k] * d * d), p);
        }
        out[PHI_OFF + (size_t)b * SEQ + u] = p;
        phi_ws[(size_t)b * SEQ + u] = p;
    }
}

// ---------------- k2: wind[b,v] = sum_u phi[b,u] * sh[b,u,v] ----------------
// grid: BATCH * 4 blocks; each block handles 256 u-rows of one batch slice.
__global__ __launch_bounds__(256) void wind_einsum(
    const float4* __restrict__ sh4,    // [B, U, V/4]
    const float*  __restrict__ phi_ws, // [B, SEQ]
    float*        __restrict__ out)
{
    const int b   = blockIdx.x >> 2;
    const int uc  = blockIdx.x & 3;     // u-chunk: 256 rows
    const int tid = threadIdx.x;

    __shared__ float phi_s[256];
    __shared__ float red[8][VOCAB];

    phi_s[tid] = phi_ws[(size_t)b * SEQ + uc * 256 + tid];
    __syncthreads();

    const int vq = tid & 31;   // float4 column: v = 4*vq..4*vq+3
    const int ug = tid >> 5;   // 0..7
    const float4* base = sh4 + ((size_t)b * SEQ + uc * 256) * (VOCAB / 4);

    float4 acc = make_float4(0.f, 0.f, 0.f, 0.f);
    #pragma unroll 8
    for (int i = 0; i < 32; ++i) {
        int u = ug + 8 * i;                      // 0..255 within chunk
        float4 s = base[(size_t)u * (VOCAB / 4) + vq];
        float  p = phi_s[u];
        acc.x = fmaf(p, s.x, acc.x);
        acc.y = fmaf(p, s.y, acc.y);
        acc.z = fmaf(p, s.z, acc.z);
        acc.w = fmaf(p, s.w, acc.w);
    }
    *(float4*)&red[ug][vq * 4] = acc;
    __syncthreads();

    if (tid < VOCAB) {
        float s = 0.f;
        #pragma unroll
        for (int g = 0; g < 8; ++g) s += red[g][tid];
        atomicAdd(&out[WIND_OFF + (size_t)b * VOCAB + tid], s);
    }
}

extern "C" void kernel_launch(void* const* d_in, const int* in_sizes, int n_in,
                              void* d_out, int out_size, void* d_ws, size_t ws_size,
                              hipStream_t stream) {
    const float*  win   = (const float*)d_in[0];
    const float4* sh4   = (const float4*)d_in[1];
    const float*  kprev = (const float*)d_in[2];
    const float*  W     = (const float*)d_in[3];
    const float*  bias  = (const float*)d_in[4];
    float* out    = (float*)d_out;
    float* phi_ws = (float*)d_ws;   // 2 MB of the workspace

    gates_phi<<<dim3(BATCH), dim3(256), 0, stream>>>(win, kprev, W, bias, out, phi_ws);
    wind_einsum<<<dim3(BATCH * 4), dim3(256), 0, stream>>>(sh4, phi_ws, out);
}

// Round 3
// 356.025 us; speedup vs baseline: 1.0749x; 1.0749x over previous
//
#include <hip/hip_runtime.h>

#define HIDDEN 1024
#define NG 20
#define BATCH 512
#define SEQ 1024
#define VOCAB 128

// output offsets (flat concat of (wind, kappa, phi))
#define WIND_OFF  0
#define KAPPA_OFF (BATCH * VOCAB)                 // 65536
#define PHI_OFF   (BATCH * VOCAB + BATCH * NG)    // 75776

typedef float f4 __attribute__((ext_vector_type(4)));

// ---------------- k1: linear + gates + phi (one block per batch row) --------
__global__ __launch_bounds__(256) void gates_phi(
    const float* __restrict__ win,    // [B, H]
    const float* __restrict__ kprev,  // [B, NG]
    const float* __restrict__ W,      // [3*NG, H]
    const float* __restrict__ bias,   // [3*NG]
    float*       __restrict__ out)    // wind | kappa | phi
{
    const int b    = blockIdx.x;
    const int tid  = threadIdx.x;
    const int lane = tid & 63;
    const int wave = tid >> 6;   // 0..3

    __shared__ float lin_s[3 * NG];
    __shared__ float alpha_s[NG], beta_s[NG], kappa_s[NG];

    // zero the wind accumulator region (k2 atomicAdds into it)
    if (tid < VOCAB) out[WIND_OFF + (size_t)b * VOCAB + tid] = 0.f;

    // Phase A: lin[j] = win[b,:] . W[j,:] + bias[j]  (wave per j)
    const float* wrow = win + (size_t)b * HIDDEN;
    for (int j = wave; j < 3 * NG; j += 4) {
        const float* Wrow = W + (size_t)j * HIDDEN;
        float acc = 0.f;
        #pragma unroll
        for (int t = 0; t < HIDDEN / 64; ++t)
            acc = fmaf(wrow[t * 64 + lane], Wrow[t * 64 + lane], acc);
        #pragma unroll
        for (int off = 32; off > 0; off >>= 1)
            acc += __shfl_down(acc, off, 64);
        if (lane == 0) lin_s[j] = acc + bias[j];
    }
    __syncthreads();

    // Phase B: gates
    if (tid < 3 * NG) {
        float e = __expf(lin_s[tid]);
        if (tid < NG) {
            alpha_s[tid] = e;
        } else if (tid < 2 * NG) {
            beta_s[tid - NG] = e;
        } else {
            int k = tid - 2 * NG;
            float kp = kprev[(size_t)b * NG + k] + e * 0.05f;
            kappa_s[k] = kp;
            out[KAPPA_OFF + (size_t)b * NG + k] = kp;
        }
    }
    __syncthreads();

    // Phase C: phi[u] -> out (k2 reads it back from there; it stays L2-hot)
    for (int u = tid; u < SEQ; u += 256) {
        float uu = (float)u;
        float p = 0.f;
        #pragma unroll
        for (int k = 0; k < NG; ++k) {
            float d = kappa_s[k] - uu;
            p = fmaf(alpha_s[k], __expf(-beta_s[k] * d * d), p);
        }
        out[PHI_OFF + (size_t)b * SEQ + u] = p;
    }
}

// ---------------- k2: wind[b,v] = sum_u phi[b,u] * sh[b,u,v] ----------------
// grid: BATCH * 4 blocks; each block handles 256 u-rows of one batch slice.
__global__ __launch_bounds__(256) void wind_einsum(
    const f4*    __restrict__ sh4,   // [B, U, V/4]
    const float* __restrict__ phi,   // = out + PHI_OFF, [B, SEQ]
    float*       __restrict__ wind)  // = out + WIND_OFF, [B, V]
{
    const int b   = blockIdx.x >> 2;
    const int uc  = blockIdx.x & 3;     // u-chunk: 256 rows
    const int tid = threadIdx.x;

    __shared__ float phi_s[256];
    __shared__ float red[8][VOCAB];

    phi_s[tid] = phi[(size_t)b * SEQ + uc * 256 + tid];
    __syncthreads();

    const int vq = tid & 31;   // float4 column: v = 4*vq..4*vq+3
    const int ug = tid >> 5;   // 0..7
    const f4* base = sh4 + ((size_t)b * SEQ + uc * 256) * (VOCAB / 4);

    f4 acc = (f4){0.f, 0.f, 0.f, 0.f};
    #pragma unroll 8
    for (int i = 0; i < 32; ++i) {
        int u = ug + 8 * i;                      // 0..255 within chunk
        f4 s = __builtin_nontemporal_load(base + (size_t)u * (VOCAB / 4) + vq);
        acc += phi_s[u] * s;
    }
    *(f4*)&red[ug][vq * 4] = acc;
    __syncthreads();

    if (tid < VOCAB) {
        float s = 0.f;
        #pragma unroll
        for (int g = 0; g < 8; ++g) s += red[g][tid];
        atomicAdd(&wind[(size_t)b * VOCAB + tid], s);
    }
}

extern "C" void kernel_launch(void* const* d_in, const int* in_sizes, int n_in,
                              void* d_out, int out_size, void* d_ws, size_t ws_size,
                              hipStream_t stream) {
    const float* win   = (const float*)d_in[0];
    const f4*    sh4   = (const f4*)d_in[1];
    const float* kprev = (const float*)d_in[2];
    const float* W     = (const float*)d_in[3];
    const float* bias  = (const float*)d_in[4];
    float* out = (float*)d_out;

    gates_phi<<<dim3(BATCH), dim3(256), 0, stream>>>(win, kprev, W, bias, out);
    wind_einsum<<<dim3(BATCH * 4), dim3(256), 0, stream>>>(
        sh4, out + PHI_OFF, out + WIND_OFF);
}

// Round 4
// 354.018 us; speedup vs baseline: 1.0810x; 1.0057x over previous
//
#include <hip/hip_runtime.h>

#define HIDDEN 1024
#define NG 20
#define BATCH 512
#define SEQ 1024
#define VOCAB 128

// output offsets (flat concat of (wind, kappa, phi))
#define WIND_OFF  0
#define KAPPA_OFF (BATCH * VOCAB)                 // 65536
#define PHI_OFF   (BATCH * VOCAB + BATCH * NG)    // 75776

typedef float f4 __attribute__((ext_vector_type(4)));

// ws layout: alpha [B][NG] | beta [B][NG] | kappa [B][NG]
#define WS_ALPHA 0
#define WS_BETA  (BATCH * NG)
#define WS_KAPPA (2 * BATCH * NG)

// ---------------- k1: linear + gates (one block per batch row) --------------
__global__ __launch_bounds__(256) void gates_k(
    const f4*    __restrict__ win4,   // [B, H/4]
    const float* __restrict__ kprev,  // [B, NG]
    const f4*    __restrict__ W4,     // [3*NG, H/4]
    const float* __restrict__ bias,   // [3*NG]
    float*       __restrict__ out,    // wind | kappa | phi
    float*       __restrict__ ws)     // gates
{
    const int b    = blockIdx.x;
    const int tid  = threadIdx.x;
    const int lane = tid & 63;
    const int wave = tid >> 6;   // 0..3

    __shared__ float lin_s[3 * NG];

    // zero the wind accumulator region (k2 atomicAdds into it)
    if (tid < VOCAB) out[WIND_OFF + (size_t)b * VOCAB + tid] = 0.f;

    // lin[j] = win[b,:] . W[j,:] + bias[j]  (wave per j, float4 loads)
    const f4* wrow = win4 + (size_t)b * (HIDDEN / 4);
    for (int j = wave; j < 3 * NG; j += 4) {
        const f4* Wrow = W4 + (size_t)j * (HIDDEN / 4);
        float acc = 0.f;
        #pragma unroll
        for (int t = 0; t < HIDDEN / 4 / 64; ++t) {     // 4 iters
            f4 a = wrow[t * 64 + lane];
            f4 w = Wrow[t * 64 + lane];
            acc = fmaf(a.x, w.x, acc);
            acc = fmaf(a.y, w.y, acc);
            acc = fmaf(a.z, w.z, acc);
            acc = fmaf(a.w, w.w, acc);
        }
        #pragma unroll
        for (int off = 32; off > 0; off >>= 1)
            acc += __shfl_down(acc, off, 64);
        if (lane == 0) lin_s[j] = acc + bias[j];
    }
    __syncthreads();

    // gates -> ws (and kappa -> out)
    if (tid < 3 * NG) {
        float e = __expf(lin_s[tid]);
        if (tid < NG) {
            ws[WS_ALPHA + (size_t)b * NG + tid] = e;
        } else if (tid < 2 * NG) {
            ws[WS_BETA + (size_t)b * NG + (tid - NG)] = e;
        } else {
            int k = tid - 2 * NG;
            float kp = kprev[(size_t)b * NG + k] + e * 0.05f;
            ws[WS_KAPPA + (size_t)b * NG + k] = kp;
            out[KAPPA_OFF + (size_t)b * NG + k] = kp;
        }
    }
}

// -------- k2: phi chunk + wind[b,v] = sum_u phi[b,u] * sh[b,u,v] ------------
// grid: BATCH*4 blocks; each block: 256 u-rows of one batch slice.
__global__ __launch_bounds__(256) void phi_wind_k(
    const f4*    __restrict__ sh4,   // [B, U, V/4]
    const float* __restrict__ ws,    // gates
    float*       __restrict__ out)   // wind | kappa | phi
{
    const int b   = blockIdx.x >> 2;
    const int uc  = blockIdx.x & 3;     // u-chunk: 256 rows
    const int tid = threadIdx.x;

    __shared__ float alpha_s[NG], beta_s[NG], kappa_s[NG];
    __shared__ float phi_s[256];
    __shared__ float red[8][VOCAB];

    if (tid < NG)                 alpha_s[tid]          = ws[WS_ALPHA + (size_t)b * NG + tid];
    else if (tid < 2 * NG)        beta_s[tid - NG]      = ws[WS_BETA  + (size_t)b * NG + (tid - NG)];
    else if (tid < 3 * NG)        kappa_s[tid - 2 * NG] = ws[WS_KAPPA + (size_t)b * NG + (tid - 2 * NG)];
    __syncthreads();

    // phi for this chunk's 256 u values
    {
        const float uu = (float)(uc * 256 + tid);
        float p = 0.f;
        #pragma unroll
        for (int k = 0; k < NG; ++k) {
            float d = kappa_s[k] - uu;
            p = fmaf(alpha_s[k], __expf(-beta_s[k] * d * d), p);
        }
        phi_s[tid] = p;
        out[PHI_OFF + (size_t)b * SEQ + uc * 256 + tid] = p;
    }
    __syncthreads();

    // streaming einsum over this chunk
    const int vq = tid & 31;   // float4 column: v = 4*vq..4*vq+3
    const int ug = tid >> 5;   // 0..7
    const f4* base = sh4 + ((size_t)b * SEQ + uc * 256) * (VOCAB / 4);

    f4 acc = (f4){0.f, 0.f, 0.f, 0.f};
    #pragma unroll 8
    for (int i = 0; i < 32; ++i) {
        int u = ug + 8 * i;                      // 0..255 within chunk
        f4 s = __builtin_nontemporal_load(base + (size_t)u * (VOCAB / 4) + vq);
        acc += phi_s[u] * s;
    }
    *(f4*)&red[ug][vq * 4] = acc;
    __syncthreads();

    if (tid < VOCAB) {
        float s = 0.f;
        #pragma unroll
        for (int g = 0; g < 8; ++g) s += red[g][tid];
        atomicAdd(&out[WIND_OFF + (size_t)b * VOCAB + tid], s);
    }
}

extern "C" void kernel_launch(void* const* d_in, const int* in_sizes, int n_in,
                              void* d_out, int out_size, void* d_ws, size_t ws_size,
                              hipStream_t stream) {
    const f4*    win4  = (const f4*)d_in[0];
    const f4*    sh4   = (const f4*)d_in[1];
    const float* kprev = (const float*)d_in[2];
    const f4*    W4    = (const f4*)d_in[3];
    const float* bias  = (const float*)d_in[4];
    float* out = (float*)d_out;
    float* ws  = (float*)d_ws;

    gates_k<<<dim3(BATCH), dim3(256), 0, stream>>>(win4, kprev, W4, bias, out, ws);
    phi_wind_k<<<dim3(BATCH * 4), dim3(256), 0, stream>>>(sh4, ws, out);
}